// Round 20
// baseline (504.297 us; speedup 1.0000x reference)
//
#include <hip/hip_runtime.h>
#include <math.h>

#define BB 2
#define NN 20000
#define EE 100000
#define DD 3
#define KK 128
#define CC 128
#define LL 3
#define FCC 128
#define GJ (DD*CC)    // 384
#define KR 768        // stacked contraction: 128 bc + 128 bs + 128 h + 384 g
#define NP 20096      // padded N: 157 tiles * 128
#define NCHK 157      // 128-row chunks
#define G1CH 40       // gemm1 split-k chunks (512 n each; last partial, zero-filled)
#define G1N 512

typedef __attribute__((ext_vector_type(8))) short bf16x8;
typedef __attribute__((ext_vector_type(4))) float f32x4;

__device__ inline unsigned short f2bf(float f) {
  unsigned int u = __float_as_uint(f);
  u += 0x7fffu + ((u >> 16) & 1u);
  return (unsigned short)(u >> 16);
}
__device__ inline float bf2f(unsigned short u) {
  return __uint_as_float(((unsigned int)u) << 16);
}

// ---- scratch (device globals) ----
__device__ float d_nw[BB*NN];
__device__ __align__(16) unsigned short d_stackT[(size_t)BB*NP*KR]; // [b][n][r] bf16: 0 bc,128 bs,256 h,384 g
__device__ __align__(16) unsigned short d_bcT[(size_t)BB*KK*NP];    // [b][k][n] bf16, pad-zeroed
__device__ __align__(16) unsigned short d_bsT[(size_t)BB*KK*NP];
__device__ __align__(16) unsigned short d_hTwT[(size_t)BB*CC*NP];   // [b][c][n] bf16 = h*nw, pad-zeroed
__device__ __align__(16) unsigned short d_Amatb[BB*CC*KR];  // [b][o][r] bf16
__device__ __align__(16) unsigned short d_fc1wb[FCC*CC];    // [o2][c] bf16
__device__ __align__(16) float d_part[(size_t)BB*4*G1CH*2*64*64];   // [b][quad][chunk][arr][c*64+k]
__device__ float d_xc[BB*CC*KK];
__device__ float d_xs[BB*CC*KK];
__device__ float d_x0p[BB*NCHK*CC];
__device__ float d_fcp[BB*CC*8*KK];   // spec partials [b][o][ch][k]
__device__ float d_fsp[BB*CC*8*KK];
__device__ float d_bias[BB*CC];
// CSR
__device__ int d_cnt[BB*NN];
__device__ int d_cursor[BB*NN];
__device__ int d_off[BB*(NN+1)];
__device__ __align__(16) float4 d_erec[(size_t)BB*EE];      // {dst_bits, w0, w1, w2}

// ---- basis -> stackT bc/bs slabs (bf16) ----
__global__ __launch_bounds__(128) void k_basis(const float* __restrict__ nodes,
                                               const float* __restrict__ nodew,
                                               const float* __restrict__ modes,
                                               const float* __restrict__ spL) {
  int bn = blockIdx.x;            // b*NN + n
  int k  = threadIdx.x;
  int b = bn / NN, n = bn % NN;
  float x0 = nodes[bn*3+0], x1 = nodes[bn*3+1], x2 = nodes[bn*3+2];
  float tmp = x0*modes[k*3+0]*spL[0] + x1*modes[k*3+1]*spL[1] + x2*modes[k*3+2]*spL[2];
  float cv = cosf(tmp), sv = sinf(tmp);
  size_t row = (size_t)(b*NP + n);
  d_stackT[row*KR + k]       = f2bf(cv);
  d_stackT[row*KR + 128 + k] = f2bf(sv);
  if (k == 0) d_nw[bn] = nodew[bn];
}

// ---- transpose stackT bc/bs slabs -> bcT/bsT [k][n] bf16 (once; zero-pads n>=NN) ----
__global__ __launch_bounds__(256) void k_basisT() {
  __shared__ unsigned short t1[32][136];
  __shared__ unsigned short t2[32][136];
  int blk = blockIdx.x;          // 628 * BB
  int nt = blk % 628, b = blk / 628;
  int n0 = nt*32;
  int tid = threadIdx.x;
  int kl = tid & 127, ng = tid >> 7;
  for (int nn = ng; nn < 32; nn += 2) {
    int n = n0 + nn;
    unsigned short cv = 0, sv = 0;
    if (n < NN) {
      const unsigned short* sp = d_stackT + ((size_t)(b*NP + n))*KR;
      cv = sp[kl]; sv = sp[128 + kl];
    }
    t1[nn][kl] = cv;
    t2[nn][kl] = sv;
  }
  __syncthreads();
  int nl = tid & 31, kg = tid >> 5;
  for (int k = kg; k < 128; k += 8) {
    d_bcT[((size_t)(b*KK + k))*NP + n0 + nl] = t1[nl][k];
    d_bsT[((size_t)(b*KK + k))*NP + n0 + nl] = t2[nl][k];
  }
}

// ---- CSR build ----
__global__ __launch_bounds__(256) void k_csr_zero() {
  int tid = blockIdx.x*256 + threadIdx.x;
  if (tid < BB*NN) { d_cnt[tid] = 0; d_cursor[tid] = 0; }
}

__global__ __launch_bounds__(256) void k_csr_count(const int* __restrict__ edges) {
  int e = blockIdx.x*256 + threadIdx.x;
  if (e >= BB*EE) return;
  int b = e / EE;
  int src = edges[e*2 + 0];
  atomicAdd(&d_cnt[b*NN + src], 1);
}

__global__ __launch_bounds__(1024) void k_csr_scan() {
  int b = blockIdx.x;
  __shared__ int sdata[1024];
  __shared__ int carry_s;
  int tid = threadIdx.x;
  if (tid == 0) carry_s = 0;
  __syncthreads();
  for (int chunk = 0; chunk < 20; ++chunk) {
    int i = chunk*1024 + tid;
    int v = (i < NN) ? d_cnt[b*NN + i] : 0;
    sdata[tid] = v;
    __syncthreads();
    for (int s = 1; s < 1024; s <<= 1) {
      int tv = (tid >= s) ? sdata[tid - s] : 0;
      __syncthreads();
      sdata[tid] += tv;
      __syncthreads();
    }
    int excl = carry_s + sdata[tid] - v;
    if (i < NN) d_off[b*(NN+1) + i] = excl;
    __syncthreads();
    if (tid == 1023) carry_s += sdata[1023];
    __syncthreads();
  }
  if (tid == 0) d_off[b*(NN+1) + NN] = carry_s;
}

// ---- scatter: build packed edge records {dst, w0, w1, w2} ----
__global__ __launch_bounds__(256) void k_csr_scatter(const int* __restrict__ edges,
                                                     const float* __restrict__ egw) {
  int e = blockIdx.x*256 + threadIdx.x;
  if (e >= BB*EE) return;
  int b = e / EE;
  int src = edges[e*2 + 0];
  int dst = edges[e*2 + 1];
  int pos = atomicAdd(&d_cursor[b*NN + src], 1);
  d_erec[(size_t)b*EE + d_off[b*(NN+1) + src] + pos] =
      make_float4(__int_as_float(dst), egw[e*3+0], egw[e*3+1], egw[e*3+2]);
}

// ---- fc0 -> stackT h slab (bf16) ----
__global__ __launch_bounds__(256) void k_h0(const float* __restrict__ x,
                                            const float* __restrict__ t,
                                            const float* __restrict__ w,
                                            const float* __restrict__ bias) {
  int tid = blockIdx.x*256 + threadIdx.x;   // (b*NN+n)*CC + c
  int c = tid & 127;
  int bn = tid >> 7;
  int b = bn / NN, n = bn % NN;
  const float* xv = x + bn*3;
  float acc = bias[c] + xv[0]*w[c] + xv[1]*w[CC+c] + xv[2]*w[2*CC+c]
            + t[bn]*w[3*CC+c];
  d_stackT[((size_t)(b*NP + n))*KR + 256 + c] = f2bf(acc);
}

// ---- layer-0 hTwT: stackT h slab (bf16) * nw -> bf16 [c][n], zero-pads ----
__global__ __launch_bounds__(256) void k_hT0() {
  __shared__ unsigned short t[128][136];
  int chunk = blockIdx.x;   // NCHK
  int b = blockIdx.y;
  int n0 = chunk*128;
  int tid = threadIdx.x;
  int cl = tid & 127, ng = tid >> 7;
  for (int nn = ng; nn < 128; nn += 2) {
    int n = n0 + nn;
    unsigned short v = 0;
    if (n < NN) {
      float hv = bf2f(d_stackT[((size_t)(b*NP + n))*KR + 256 + cl]);
      v = f2bf(hv * d_nw[b*NN + n]);
    }
    t[nn][cl] = v;
  }
  __syncthreads();
  int nl = tid & 31, cg = tid >> 5;
  for (int c = cg; c < 128; c += 8)
    for (int nn2 = 0; nn2 < 128; nn2 += 32)
      d_hTwT[((size_t)(b*CC + c))*NP + n0 + nn2 + nl] = t[nn2 + nl][c];
}

// ---- gemm1 MFMA: output-split split-K (64c x 64k quadrant over 512 n), dbuf ----
__global__ __launch_bounds__(256) void k_gemm1m() {
  __shared__ unsigned short Ash[2][64*40];
  __shared__ unsigned short Bch[2][64*40];
  __shared__ unsigned short Bsh[2][64*40];
  int chunk = blockIdx.x;   // G1CH
  int quad  = blockIdx.y;   // 0..3
  int b     = blockIdx.z;
  int ch = quad >> 1, kh = quad & 1;
  int tid = threadIdx.x, lane = tid & 63, wid = tid >> 6;
  int q = lane >> 4, m = lane & 15;
  f32x4 accC[4], accS[4];
  #pragma unroll
  for (int j = 0; j < 4; j++) { accC[j] = (f32x4){0.f,0.f,0.f,0.f}; accS[j] = (f32x4){0.f,0.f,0.f,0.f}; }
  const unsigned short* Ab  = d_hTwT + ((size_t)(b*CC + ch*64))*NP;
  const unsigned short* Bcp = d_bcT + ((size_t)(b*KK + kh*64))*NP;
  const unsigned short* Bsp = d_bsT + ((size_t)(b*KK + kh*64))*NP;
  int n0 = chunk*G1N;

#define G1STAGE(nb, d) { \
    int row_ = tid >> 2; int e8_ = (tid & 3)*8; \
    if ((nb) < NP) { \
      *(uint4*)&Ash[d][row_*40 + e8_] = *(const uint4*)(Ab  + (size_t)row_*NP + (nb) + e8_); \
      *(uint4*)&Bch[d][row_*40 + e8_] = *(const uint4*)(Bcp + (size_t)row_*NP + (nb) + e8_); \
      *(uint4*)&Bsh[d][row_*40 + e8_] = *(const uint4*)(Bsp + (size_t)row_*NP + (nb) + e8_); \
    } else { \
      uint4 z_ = make_uint4(0,0,0,0); \
      *(uint4*)&Ash[d][row_*40 + e8_] = z_; \
      *(uint4*)&Bch[d][row_*40 + e8_] = z_; \
      *(uint4*)&Bsh[d][row_*40 + e8_] = z_; \
    } }

  G1STAGE(n0, 0)
  int cur = 0;
  for (int s = 0; s < G1N/32; s++) {
    __syncthreads();
    if (s + 1 < G1N/32) G1STAGE(n0 + (s+1)*32, cur ^ 1)
    bf16x8 a = *(const bf16x8*)&Ash[cur][(wid*16 + m)*40 + q*8];
    #pragma unroll
    for (int kt = 0; kt < 4; kt++) {
      bf16x8 bcf = *(const bf16x8*)&Bch[cur][(kt*16 + m)*40 + q*8];
      accC[kt] = __builtin_amdgcn_mfma_f32_16x16x32_bf16(a, bcf, accC[kt], 0, 0, 0);
      bf16x8 bsf = *(const bf16x8*)&Bsh[cur][(kt*16 + m)*40 + q*8];
      accS[kt] = __builtin_amdgcn_mfma_f32_16x16x32_bf16(a, bsf, accS[kt], 0, 0, 0);
    }
    cur ^= 1;
  }
#undef G1STAGE

  float* base = d_part + ((size_t)(b*4 + quad)*G1CH + chunk)*2*4096;
  #pragma unroll
  for (int kt = 0; kt < 4; kt++)
    #pragma unroll
    for (int r = 0; r < 4; r++) {
      int c = wid*16 + q*4 + r;   // local 0..63
      int k = kt*16 + m;          // local 0..63
      base[c*64 + k]        =  accC[kt][r];
      base[4096 + c*64 + k] = -accS[kt][r];   // xs = -sum
    }
}

// ---- CSR edge gradient: 2 nodes per 256-thr block -> stackT g slab ----
__global__ __launch_bounds__(256) void k_grad_csr() {
  int bn = blockIdx.x*2 + (threadIdx.x >> 7);   // b*NN + n
  int c = threadIdx.x & 127;
  int b = bn / NN, n = bn % NN;
  int beg = d_off[b*(NN+1) + n];
  int end = d_off[b*(NN+1) + n + 1];
  const float4* rp = d_erec + (size_t)b*EE;
  const unsigned short* hb = d_stackT + (size_t)b*NP*KR + 256 + c;
  float a0 = 0.f, a1 = 0.f, a2 = 0.f;
  float sw0 = 0.f, sw1 = 0.f, sw2 = 0.f;
  int p = beg;
  for (; p + 4 <= end; p += 4) {
    float4 r1 = rp[p], r2 = rp[p+1], r3 = rp[p+2], r4 = rp[p+3];
    float f1 = bf2f(hb[(size_t)__float_as_int(r1.x)*KR]);
    float f2 = bf2f(hb[(size_t)__float_as_int(r2.x)*KR]);
    float f3 = bf2f(hb[(size_t)__float_as_int(r3.x)*KR]);
    float f4 = bf2f(hb[(size_t)__float_as_int(r4.x)*KR]);
    a0 += r1.y*f1 + r2.y*f2 + r3.y*f3 + r4.y*f4;
    a1 += r1.z*f1 + r2.z*f2 + r3.z*f3 + r4.z*f4;
    a2 += r1.w*f1 + r2.w*f2 + r3.w*f3 + r4.w*f4;
    sw0 += r1.y + r2.y + r3.y + r4.y;
    sw1 += r1.z + r2.z + r3.z + r4.z;
    sw2 += r1.w + r2.w + r3.w + r4.w;
  }
  for (; p < end; ++p) {
    float4 r1 = rp[p];
    float f1 = bf2f(hb[(size_t)__float_as_int(r1.x)*KR]);
    a0 += r1.y*f1; a1 += r1.z*f1; a2 += r1.w*f1;
    sw0 += r1.y; sw1 += r1.z; sw2 += r1.w;
  }
  float fs = bf2f(hb[(size_t)n*KR]);
  a0 -= sw0*fs; a1 -= sw1*fs; a2 -= sw2*fs;
  unsigned short* gp = d_stackT + ((size_t)(b*NP + n))*KR + 384;
  gp[c]        = f2bf(a0/(1.f + fabsf(a0)));
  gp[CC + c]   = f2bf(a1/(1.f + fabsf(a1)));
  gp[2*CC + c] = f2bf(a2/(1.f + fabsf(a2)));
}

// ---- fused: reduce split-k partials -> xc/xs  |  x0 partials from hTwT ----
__global__ __launch_bounds__(256) void k_red_x0() {
  int blk = blockIdx.x;
  if (blk < 256) {
    int tid = blk*256 + threadIdx.x;
    int k = tid & 127;
    int c = (tid >> 7) & 127;
    int arr = (tid >> 14) & 1;
    int b = tid >> 15;
    int ch = c >> 6, cl = c & 63;
    int kh = k >> 6, kl = k & 63;
    int quad = ch*2 + kh;
    const float* p = d_part + ((size_t)(b*4 + quad)*G1CH)*2*4096 + arr*4096 + cl*64 + kl;
    float acc = 0.f;
    for (int t = 0; t < G1CH; t++) acc += p[(size_t)t*2*4096];
    if (arr == 0) d_xc[(b*CC + c)*KK + k] = acc;
    else          d_xs[(b*CC + c)*KK + k] = acc;
  } else {
    int bc = blk - 256;        // 0..313
    int chunk = bc % NCHK, b = bc / NCHK;
    int tid = threadIdx.x;
    int c = tid >> 1, half = tid & 1;
    const unsigned short* p = d_hTwT + ((size_t)(b*CC + c))*NP + chunk*128 + half*64;
    float acc = 0.f;
    #pragma unroll
    for (int i = 0; i < 8; i++) {
      ushort4 v0 = *(const ushort4*)&p[i*8];
      ushort4 v1 = *(const ushort4*)&p[i*8 + 4];
      acc += bf2f(v0.x) + bf2f(v0.y) + bf2f(v0.z) + bf2f(v0.w)
           + bf2f(v1.x) + bf2f(v1.y) + bf2f(v1.z) + bf2f(v1.w);
    }
    __shared__ float red[128][2];
    red[c][half] = acc;
    __syncthreads();
    if (half == 0) d_x0p[(b*NCHK + chunk)*CC + c] = red[c][0] + red[c][1];
  }
}

// ---- spectral mix, i-chunked (8 chunks of 16) -> partials ----
__global__ __launch_bounds__(128) void k_spec(const float* __restrict__ Wc,
                                              const float* __restrict__ Ws, int l) {
  int bo = blockIdx.x;          // b*CC + o
  int ch = blockIdx.y;          // 0..7
  int b = bo >> 7;
  int o = bo & 127;
  int k = threadIdx.x;
  int i0 = ch*16;
  const float* wcp = Wc + ((size_t)(l*CC + i0)*CC + o)*KK + k;
  const float* wsp = Ws + ((size_t)(l*CC + i0)*CC + o)*KK + k;
  float fc = 0.f, fs = 0.f;
  #pragma unroll 4
  for (int j = 0; j < 16; j++) {
    int i = i0 + j;
    float xcv = d_xc[(b*CC + i)*KK + k];
    float xsv = d_xs[(b*CC + i)*KK + k];
    float wcv = wcp[(size_t)j*CC*KK];
    float wsv = wsp[(size_t)j*CC*KK];
    fc += xcv*wcv - xsv*wsv;
    fs += xsv*wcv + xcv*wsv;
  }
  d_fcp[((size_t)bo*8 + ch)*KK + k] = fc;
  d_fsp[((size_t)bo*8 + ch)*KK + k] = fs;
}

// ---- fused: build A matrix [b][o][r] bf16  |  f0 + full bias ----
__global__ __launch_bounds__(128) void k_bA_f0(const float* __restrict__ wsw,
                                               const float* __restrict__ gwsw,
                                               const float* __restrict__ W0,
                                               const float* __restrict__ wsb,
                                               const float* __restrict__ gwsb, int l) {
  int blk = blockIdx.x;
  int t = threadIdx.x;
  if (blk < 256) {
    int bo = blk;
    int b = bo >> 7, o = bo & 127;
    float fc = 0.f, fs = 0.f;
    #pragma unroll
    for (int ch = 0; ch < 8; ch++) {
      fc += d_fcp[((size_t)bo*8 + ch)*KK + t];
      fs += d_fsp[((size_t)bo*8 + ch)*KK + t];
    }
    unsigned short* dst = d_Amatb + (size_t)bo*KR;
    dst[t]       = f2bf( 2.f*fc);
    dst[128 + t] = f2bf(-2.f*fs);
    dst[256 + t] = f2bf(wsw[(l*CC + o)*CC + t]);
    #pragma unroll
    for (int j = 0; j < 3; j++)
      dst[384 + j*128 + t] = f2bf(gwsw[(size_t)(l*CC + o)*GJ + j*128 + t]);
  } else {
    int b = blk - 256;
    int o = t;
    __shared__ float sx[CC];
    float xv = 0.f;
    for (int p = 0; p < NCHK; p++) xv += d_x0p[(b*NCHK + p)*CC + o];
    sx[o] = xv;
    __syncthreads();
    float acc = 0.f;
    for (int i = 0; i < CC; i++) acc += sx[i]*W0[(l*CC + i)*CC + o];
    d_bias[b*CC + o] = acc + wsb[l*CC + o] + gwsb[l*CC + o];
  }
}

// ---- fc1w transpose to [o2][c] bf16 ----
__global__ __launch_bounds__(128) void k_fc1w(const float* __restrict__ fc1w) {
  int c = blockIdx.x;
  int o2 = threadIdx.x;
  d_fc1wb[o2*CC + c] = f2bf(fc1w[c*FCC + o2]);
}

// ---- MFMA GEMM v9 (R14 geometry + fused epilogues):
// 32n x 128o, 256 threads (4 waves = 2n x 2o), K-chunk 64, A+B LDS dbuf.
// aux=1: h-slab (coalesced via Ep) + hTwT (direct pk writes). aux=0: fc2+residual. ----
__global__ __launch_bounds__(256) void k_mfma(int koff, int K,
                                              const unsigned short* __restrict__ W, size_t wstride,
                                              const float* __restrict__ bias, int bias_stride,
                                              int gelu, int aux,
                                              const float* __restrict__ xvec,
                                              const float* __restrict__ tvec,
                                              const float* __restrict__ fc2w,
                                              const float* __restrict__ fc2b,
                                              float* __restrict__ outp) {
  __shared__ unsigned short As[2][32*72];    // 9.2 KB (aliased as Ep: 32*132=4224 <= 4608)
  __shared__ unsigned short Bs[2][128*72];   // 36.9 KB
  int b = blockIdx.z;
  int n_base = blockIdx.x*32;
  int tid = threadIdx.x;
  int lane = tid & 63, wid = tid >> 6;
  int wr = wid >> 1, wc = wid & 1;           // n-group, o-group
  int q = lane >> 4, m = lane & 15;

  f32x4 acc[4];
  #pragma unroll
  for (int j = 0; j < 4; j++) acc[j] = (f32x4){0.f,0.f,0.f,0.f};

  const unsigned short* Wb = W + (size_t)b*wstride;
  const unsigned short* Ab = d_stackT + (size_t)b*NP*KR + koff;

#define STAGE(k0, d) { \
    { int rowA = tid >> 3; int e8A = (tid & 7)*8; \
      *(uint4*)&As[d][rowA*72 + e8A] = *(const uint4*)(Ab + (size_t)(n_base + rowA)*KR + (k0) + e8A); } \
    _Pragma("unroll") \
    for (int i_ = 0; i_ < 4; i_++) { \
      int idx_ = tid + i_*256; int rowB = idx_ >> 3; int e8B = (idx_ & 7)*8; \
      *(uint4*)&Bs[d][rowB*72 + e8B] = *(const uint4*)(Wb + (size_t)rowB*K + (k0) + e8B); } }

  STAGE(0, 0)
  int cur = 0;
  for (int k0 = 0; k0 < K; k0 += 64) {
    __syncthreads();
    if (k0 + 64 < K) STAGE(k0 + 64, cur ^ 1)
    bf16x8 a0 = *(const bf16x8*)&As[cur][(wr*16 + m)*72 + q*8];
    bf16x8 a1 = *(const bf16x8*)&As[cur][(wr*16 + m)*72 + 32 + q*8];
    #pragma unroll
    for (int ot = 0; ot < 4; ot++) {
      bf16x8 b0 = *(const bf16x8*)&Bs[cur][(wc*64 + ot*16 + m)*72 + q*8];
      acc[ot] = __builtin_amdgcn_mfma_f32_16x16x32_bf16(a0, b0, acc[ot], 0, 0, 0);
      bf16x8 b1 = *(const bf16x8*)&Bs[cur][(wc*64 + ot*16 + m)*72 + 32 + q*8];
      acc[ot] = __builtin_amdgcn_mfma_f32_16x16x32_bf16(a1, b1, acc[ot], 0, 0, 0);
    }
    cur ^= 1;
  }
#undef STAGE

  // ---- epilogue: bias+gelu -> bf16 into LDS (alias dead As); hTwT direct pk ----
  __syncthreads();
  unsigned short* Ep = &As[0][0];
  const float* bp = bias + (size_t)b*bias_stride;
  int lrow = wr*16 + q*4;                    // local n row base (0..31)
  int nb4 = n_base + lrow;
  float nw4[4];
  #pragma unroll
  for (int r = 0; r < 4; r++)
    nw4[r] = (aux && nb4 + r < NN) ? d_nw[b*NN + nb4 + r] : 0.f;
  #pragma unroll
  for (int ot = 0; ot < 4; ot++) {
    int o = wc*64 + ot*16 + m;
    float bvv = bp[o];
    float vals[4];
    #pragma unroll
    for (int r = 0; r < 4; r++) {
      float v = acc[ot][r] + bvv;
      if (gelu) v = 0.5f*v*(1.f + erff(v*0.70710678118f));
      vals[r] = v;
      Ep[(lrow + r)*132 + o] = f2bf(v);
    }
    if (aux) {
      ushort4 pk;
      pk.x = f2bf(vals[0]*nw4[0]);
      pk.y = f2bf(vals[1]*nw4[1]);
      pk.z = f2bf(vals[2]*nw4[2]);
      pk.w = f2bf(vals[3]*nw4[3]);
      *(ushort4*)&d_hTwT[((size_t)(b*CC + o))*NP + nb4] = pk;
    }
  }
  __syncthreads();
  if (aux) {
    // h-slab rows: 32 rows x 128 cols, 16 ushorts/thread
    int row = tid >> 3;
    int c16 = (tid & 7)*16;
    int n = n_base + row;
    if (n < NN) {
      uint4 v0 = *(uint4*)&Ep[row*132 + c16];
      uint4 v1 = *(uint4*)&Ep[row*132 + c16 + 8];
      unsigned short* dst = d_stackT + ((size_t)(b*NP + n))*KR + 256;
      *(uint4*)&dst[c16]     = v0;
      *(uint4*)&dst[c16 + 8] = v1;
    }
  } else {
    // fused fc2 + residual: 8 threads per row reduce 128 o2
    int row = tid >> 3, j = tid & 7;
    int n = n_base + row;
    float p0 = 0.f, p1 = 0.f, p2 = 0.f;
    int o0 = j*16;
    #pragma unroll
    for (int oo = 0; oo < 16; oo++) {
      float uv = bf2f(Ep[row*132 + o0 + oo]);
      p0 += uv*fc2w[(o0+oo)*3 + 0];
      p1 += uv*fc2w[(o0+oo)*3 + 1];
      p2 += uv*fc2w[(o0+oo)*3 + 2];
    }
    #pragma unroll
    for (int s2 = 1; s2 < 8; s2 <<= 1) {
      p0 += __shfl_xor(p0, s2);
      p1 += __shfl_xor(p1, s2);
      p2 += __shfl_xor(p2, s2);
    }
    if (j == 0 && n < NN) {
      int bn = b*NN + n;
      float tv = tvec[bn];
      outp[bn*3 + 0] = xvec[bn*3 + 0] + tv*(p0 + fc2b[0]);
      outp[bn*3 + 1] = xvec[bn*3 + 1] + tv*(p1 + fc2b[1]);
      outp[bn*3 + 2] = xvec[bn*3 + 2] + tv*(p2 + fc2b[2]);
    }
  }
}

extern "C" void kernel_launch(void* const* d_in, const int* in_sizes, int n_in,
                              void* d_out, int out_size, void* d_ws, size_t ws_size,
                              hipStream_t stream) {
  const float* x     = (const float*)d_in[0];
  const float* t     = (const float*)d_in[1];
  const float* nodes = (const float*)d_in[3];
  const float* nodew = (const float*)d_in[4];
  const int*   edges = (const int*)d_in[5];
  const float* egw   = (const float*)d_in[6];
  const float* modes = (const float*)d_in[7];
  const float* spL   = (const float*)d_in[8];
  const float* fc0w  = (const float*)d_in[9];
  const float* fc0b  = (const float*)d_in[10];
  const float* Wc    = (const float*)d_in[11];
  const float* Ws    = (const float*)d_in[12];
  const float* W0    = (const float*)d_in[13];
  const float* wsw   = (const float*)d_in[14];
  const float* wsb   = (const float*)d_in[15];
  const float* gwsw  = (const float*)d_in[16];
  const float* gwsb  = (const float*)d_in[17];
  const float* fc1w  = (const float*)d_in[18];
  const float* fc1b  = (const float*)d_in[19];
  const float* fc2w  = (const float*)d_in[20];
  const float* fc2b  = (const float*)d_in[21];
  float* out = (float*)d_out;

  unsigned short* d_Amatb_p; (void)hipGetSymbolAddress((void**)&d_Amatb_p, HIP_SYMBOL(d_Amatb));
  unsigned short* d_fc1wb_p; (void)hipGetSymbolAddress((void**)&d_fc1wb_p, HIP_SYMBOL(d_fc1wb));
  float* d_bias_p;  (void)hipGetSymbolAddress((void**)&d_bias_p,  HIP_SYMBOL(d_bias));

  hipLaunchKernelGGL(k_basis, dim3(BB*NN), dim3(128), 0, stream, nodes, nodew, modes, spL);
  hipLaunchKernelGGL(k_basisT, dim3(628*BB), dim3(256), 0, stream);
  hipLaunchKernelGGL(k_h0, dim3(BB*NN*CC/256), dim3(256), 0, stream, x, t, fc0w, fc0b);
  hipLaunchKernelGGL(k_hT0, dim3(NCHK, BB), dim3(256), 0, stream);
  hipLaunchKernelGGL(k_fc1w, dim3(CC), dim3(FCC), 0, stream, fc1w);
  // CSR build (once; edges constant across layers)
  hipLaunchKernelGGL(k_csr_zero, dim3((BB*NN + 255)/256), dim3(256), 0, stream);
  hipLaunchKernelGGL(k_csr_count, dim3((BB*EE + 255)/256), dim3(256), 0, stream, edges);
  hipLaunchKernelGGL(k_csr_scan, dim3(BB), dim3(1024), 0, stream);
  hipLaunchKernelGGL(k_csr_scatter, dim3((BB*EE + 255)/256), dim3(256), 0, stream, edges, egw);

  for (int l = 0; l < LL; l++) {
    hipLaunchKernelGGL(k_gemm1m, dim3(G1CH, 4, BB), dim3(256), 0, stream);
    hipLaunchKernelGGL(k_grad_csr, dim3(BB*NN/2), dim3(256), 0, stream);
    hipLaunchKernelGGL(k_red_x0, dim3(256 + NCHK*BB), dim3(256), 0, stream);
    hipLaunchKernelGGL(k_spec, dim3(BB*CC, 8), dim3(128), 0, stream, Wc, Ws, l);
    hipLaunchKernelGGL(k_bA_f0, dim3(BB*CC + BB), dim3(128), 0, stream,
                       wsw, gwsw, W0, wsb, gwsb, l);
    hipLaunchKernelGGL(k_mfma, dim3(NP/32, 1, BB), dim3(256), 0, stream,
                       0, KR, d_Amatb_p, (size_t)CC*KR, d_bias_p, CC,
                       (l != LL-1) ? 1 : 0, 1,
                       (const float*)nullptr, (const float*)nullptr,
                       (const float*)nullptr, (const float*)nullptr, (float*)nullptr);
  }

  // fc1 via MFMA on the h slab, fc2+residual fused in epilogue (gelu=1, aux=0)
  hipLaunchKernelGGL(k_mfma, dim3(NP/32, 1, BB), dim3(256), 0, stream,
                     256, CC, d_fc1wb_p, (size_t)0, fc1b, 0, 1, 0,
                     x, t, fc2w, fc2b, out);
}

// Round 21
// 488.051 us; speedup vs baseline: 1.0333x; 1.0333x over previous
//
#include <hip/hip_runtime.h>
#include <math.h>

#define BB 2
#define NN 20000
#define EE 100000
#define DD 3
#define KK 128
#define CC 128
#define LL 3
#define FCC 128
#define GJ (DD*CC)    // 384
#define KR 768        // stacked contraction: 128 bc + 128 bs + 128 h + 384 g
#define NP 20096      // padded N: 157 tiles * 128
#define NCHK 157      // 128-row chunks
#define G1CH 40       // gemm1 split-k chunks (512 n each; last partial, zero-filled)
#define G1N 512

typedef __attribute__((ext_vector_type(8))) short bf16x8;
typedef __attribute__((ext_vector_type(4))) float f32x4;

__device__ inline unsigned short f2bf(float f) {
  unsigned int u = __float_as_uint(f);
  u += 0x7fffu + ((u >> 16) & 1u);
  return (unsigned short)(u >> 16);
}
__device__ inline float bf2f(unsigned short u) {
  return __uint_as_float(((unsigned int)u) << 16);
}

// ---- scratch (device globals) ----
__device__ float d_nw[BB*NN];
__device__ __align__(16) unsigned short d_stackT[(size_t)BB*NP*KR]; // [b][n][r] bf16: 0 bc,128 bs,256 h,384 g
__device__ __align__(16) unsigned short d_bcT[(size_t)BB*KK*NP];    // [b][k][n] bf16, pad-zeroed
__device__ __align__(16) unsigned short d_bsT[(size_t)BB*KK*NP];
__device__ __align__(16) unsigned short d_hTwT[(size_t)BB*CC*NP];   // [b][c][n] bf16 = h*nw, pad-zeroed
__device__ __align__(16) unsigned short d_Amatb[BB*CC*KR];  // [b][o][r] bf16
__device__ __align__(16) unsigned short d_fc1wb[FCC*CC];    // [o2][c] bf16
__device__ __align__(16) float d_part[(size_t)BB*4*G1CH*2*64*64];   // [b][quad][chunk][arr][c*64+k]
__device__ float d_xc[BB*CC*KK];
__device__ float d_xs[BB*CC*KK];
__device__ float d_x0p[BB*NCHK*CC];
__device__ float d_fcp[BB*CC*8*KK];   // spec partials [b][o][ch][k]
__device__ float d_fsp[BB*CC*8*KK];
__device__ float d_bias[BB*CC];
// CSR
__device__ int d_cnt[BB*NN];
__device__ int d_cursor[BB*NN];
__device__ int d_off[BB*(NN+1)];
__device__ __align__(16) float4 d_erec[(size_t)BB*EE];      // {dst_bits, w0, w1, w2}

// ---- basis -> stackT bc/bs slabs (bf16) ----
__global__ __launch_bounds__(128) void k_basis(const float* __restrict__ nodes,
                                               const float* __restrict__ nodew,
                                               const float* __restrict__ modes,
                                               const float* __restrict__ spL) {
  int bn = blockIdx.x;            // b*NN + n
  int k  = threadIdx.x;
  int b = bn / NN, n = bn % NN;
  float x0 = nodes[bn*3+0], x1 = nodes[bn*3+1], x2 = nodes[bn*3+2];
  float tmp = x0*modes[k*3+0]*spL[0] + x1*modes[k*3+1]*spL[1] + x2*modes[k*3+2]*spL[2];
  float cv = cosf(tmp), sv = sinf(tmp);
  size_t row = (size_t)(b*NP + n);
  d_stackT[row*KR + k]       = f2bf(cv);
  d_stackT[row*KR + 128 + k] = f2bf(sv);
  if (k == 0) d_nw[bn] = nodew[bn];
}

// ---- transpose stackT bc/bs slabs -> bcT/bsT [k][n] bf16 (once; zero-pads n>=NN) ----
__global__ __launch_bounds__(256) void k_basisT() {
  __shared__ unsigned short t1[32][136];
  __shared__ unsigned short t2[32][136];
  int blk = blockIdx.x;          // 628 * BB
  int nt = blk % 628, b = blk / 628;
  int n0 = nt*32;
  int tid = threadIdx.x;
  int kl = tid & 127, ng = tid >> 7;
  for (int nn = ng; nn < 32; nn += 2) {
    int n = n0 + nn;
    unsigned short cv = 0, sv = 0;
    if (n < NN) {
      const unsigned short* sp = d_stackT + ((size_t)(b*NP + n))*KR;
      cv = sp[kl]; sv = sp[128 + kl];
    }
    t1[nn][kl] = cv;
    t2[nn][kl] = sv;
  }
  __syncthreads();
  int nl = tid & 31, kg = tid >> 5;
  for (int k = kg; k < 128; k += 8) {
    d_bcT[((size_t)(b*KK + k))*NP + n0 + nl] = t1[nl][k];
    d_bsT[((size_t)(b*KK + k))*NP + n0 + nl] = t2[nl][k];
  }
}

// ---- CSR build ----
__global__ __launch_bounds__(256) void k_csr_zero() {
  int tid = blockIdx.x*256 + threadIdx.x;
  if (tid < BB*NN) { d_cnt[tid] = 0; d_cursor[tid] = 0; }
}

__global__ __launch_bounds__(256) void k_csr_count(const int* __restrict__ edges) {
  int e = blockIdx.x*256 + threadIdx.x;
  if (e >= BB*EE) return;
  int b = e / EE;
  int src = edges[e*2 + 0];
  atomicAdd(&d_cnt[b*NN + src], 1);
}

__global__ __launch_bounds__(1024) void k_csr_scan() {
  int b = blockIdx.x;
  __shared__ int sdata[1024];
  __shared__ int carry_s;
  int tid = threadIdx.x;
  if (tid == 0) carry_s = 0;
  __syncthreads();
  for (int chunk = 0; chunk < 20; ++chunk) {
    int i = chunk*1024 + tid;
    int v = (i < NN) ? d_cnt[b*NN + i] : 0;
    sdata[tid] = v;
    __syncthreads();
    for (int s = 1; s < 1024; s <<= 1) {
      int tv = (tid >= s) ? sdata[tid - s] : 0;
      __syncthreads();
      sdata[tid] += tv;
      __syncthreads();
    }
    int excl = carry_s + sdata[tid] - v;
    if (i < NN) d_off[b*(NN+1) + i] = excl;
    __syncthreads();
    if (tid == 1023) carry_s += sdata[1023];
    __syncthreads();
  }
  if (tid == 0) d_off[b*(NN+1) + NN] = carry_s;
}

// ---- scatter: build packed edge records {dst, w0, w1, w2} ----
__global__ __launch_bounds__(256) void k_csr_scatter(const int* __restrict__ edges,
                                                     const float* __restrict__ egw) {
  int e = blockIdx.x*256 + threadIdx.x;
  if (e >= BB*EE) return;
  int b = e / EE;
  int src = edges[e*2 + 0];
  int dst = edges[e*2 + 1];
  int pos = atomicAdd(&d_cursor[b*NN + src], 1);
  d_erec[(size_t)b*EE + d_off[b*(NN+1) + src] + pos] =
      make_float4(__int_as_float(dst), egw[e*3+0], egw[e*3+1], egw[e*3+2]);
}

// ---- fc0 -> stackT h slab (bf16) ----
__global__ __launch_bounds__(256) void k_h0(const float* __restrict__ x,
                                            const float* __restrict__ t,
                                            const float* __restrict__ w,
                                            const float* __restrict__ bias) {
  int tid = blockIdx.x*256 + threadIdx.x;   // (b*NN+n)*CC + c
  int c = tid & 127;
  int bn = tid >> 7;
  int b = bn / NN, n = bn % NN;
  const float* xv = x + bn*3;
  float acc = bias[c] + xv[0]*w[c] + xv[1]*w[CC+c] + xv[2]*w[2*CC+c]
            + t[bn]*w[3*CC+c];
  d_stackT[((size_t)(b*NP + n))*KR + 256 + c] = f2bf(acc);
}

// ---- layer-0 hTwT: stackT h slab (bf16) * nw -> bf16 [c][n], zero-pads ----
__global__ __launch_bounds__(256) void k_hT0() {
  __shared__ unsigned short t[128][136];
  int chunk = blockIdx.x;   // NCHK
  int b = blockIdx.y;
  int n0 = chunk*128;
  int tid = threadIdx.x;
  int cl = tid & 127, ng = tid >> 7;
  for (int nn = ng; nn < 128; nn += 2) {
    int n = n0 + nn;
    unsigned short v = 0;
    if (n < NN) {
      float hv = bf2f(d_stackT[((size_t)(b*NP + n))*KR + 256 + cl]);
      v = f2bf(hv * d_nw[b*NN + n]);
    }
    t[nn][cl] = v;
  }
  __syncthreads();
  int nl = tid & 31, cg = tid >> 5;
  for (int c = cg; c < 128; c += 8)
    for (int nn2 = 0; nn2 < 128; nn2 += 32)
      d_hTwT[((size_t)(b*CC + c))*NP + n0 + nn2 + nl] = t[nn2 + nl][c];
}

// ---- gemm1 MFMA: output-split split-K (64c x 64k quadrant over 512 n), dbuf ----
__global__ __launch_bounds__(256) void k_gemm1m() {
  __shared__ unsigned short Ash[2][64*40];
  __shared__ unsigned short Bch[2][64*40];
  __shared__ unsigned short Bsh[2][64*40];
  int chunk = blockIdx.x;   // G1CH
  int quad  = blockIdx.y;   // 0..3
  int b     = blockIdx.z;
  int ch = quad >> 1, kh = quad & 1;
  int tid = threadIdx.x, lane = tid & 63, wid = tid >> 6;
  int q = lane >> 4, m = lane & 15;
  f32x4 accC[4], accS[4];
  #pragma unroll
  for (int j = 0; j < 4; j++) { accC[j] = (f32x4){0.f,0.f,0.f,0.f}; accS[j] = (f32x4){0.f,0.f,0.f,0.f}; }
  const unsigned short* Ab  = d_hTwT + ((size_t)(b*CC + ch*64))*NP;
  const unsigned short* Bcp = d_bcT + ((size_t)(b*KK + kh*64))*NP;
  const unsigned short* Bsp = d_bsT + ((size_t)(b*KK + kh*64))*NP;
  int n0 = chunk*G1N;

#define G1STAGE(nb, d) { \
    int row_ = tid >> 2; int e8_ = (tid & 3)*8; \
    if ((nb) < NP) { \
      *(uint4*)&Ash[d][row_*40 + e8_] = *(const uint4*)(Ab  + (size_t)row_*NP + (nb) + e8_); \
      *(uint4*)&Bch[d][row_*40 + e8_] = *(const uint4*)(Bcp + (size_t)row_*NP + (nb) + e8_); \
      *(uint4*)&Bsh[d][row_*40 + e8_] = *(const uint4*)(Bsp + (size_t)row_*NP + (nb) + e8_); \
    } else { \
      uint4 z_ = make_uint4(0,0,0,0); \
      *(uint4*)&Ash[d][row_*40 + e8_] = z_; \
      *(uint4*)&Bch[d][row_*40 + e8_] = z_; \
      *(uint4*)&Bsh[d][row_*40 + e8_] = z_; \
    } }

  G1STAGE(n0, 0)
  int cur = 0;
  for (int s = 0; s < G1N/32; s++) {
    __syncthreads();
    if (s + 1 < G1N/32) G1STAGE(n0 + (s+1)*32, cur ^ 1)
    bf16x8 a = *(const bf16x8*)&Ash[cur][(wid*16 + m)*40 + q*8];
    #pragma unroll
    for (int kt = 0; kt < 4; kt++) {
      bf16x8 bcf = *(const bf16x8*)&Bch[cur][(kt*16 + m)*40 + q*8];
      accC[kt] = __builtin_amdgcn_mfma_f32_16x16x32_bf16(a, bcf, accC[kt], 0, 0, 0);
      bf16x8 bsf = *(const bf16x8*)&Bsh[cur][(kt*16 + m)*40 + q*8];
      accS[kt] = __builtin_amdgcn_mfma_f32_16x16x32_bf16(a, bsf, accS[kt], 0, 0, 0);
    }
    cur ^= 1;
  }
#undef G1STAGE

  float* base = d_part + ((size_t)(b*4 + quad)*G1CH + chunk)*2*4096;
  #pragma unroll
  for (int kt = 0; kt < 4; kt++)
    #pragma unroll
    for (int r = 0; r < 4; r++) {
      int c = wid*16 + q*4 + r;   // local 0..63
      int k = kt*16 + m;          // local 0..63
      base[c*64 + k]        =  accC[kt][r];
      base[4096 + c*64 + k] = -accS[kt][r];   // xs = -sum
    }
}

// ---- CSR edge gradient: 2 nodes per 256-thr block -> stackT g slab ----
__global__ __launch_bounds__(256) void k_grad_csr() {
  int bn = blockIdx.x*2 + (threadIdx.x >> 7);   // b*NN + n
  int c = threadIdx.x & 127;
  int b = bn / NN, n = bn % NN;
  int beg = d_off[b*(NN+1) + n];
  int end = d_off[b*(NN+1) + n + 1];
  const float4* rp = d_erec + (size_t)b*EE;
  const unsigned short* hb = d_stackT + (size_t)b*NP*KR + 256 + c;
  float a0 = 0.f, a1 = 0.f, a2 = 0.f;
  float sw0 = 0.f, sw1 = 0.f, sw2 = 0.f;
  int p = beg;
  for (; p + 4 <= end; p += 4) {
    float4 r1 = rp[p], r2 = rp[p+1], r3 = rp[p+2], r4 = rp[p+3];
    float f1 = bf2f(hb[(size_t)__float_as_int(r1.x)*KR]);
    float f2 = bf2f(hb[(size_t)__float_as_int(r2.x)*KR]);
    float f3 = bf2f(hb[(size_t)__float_as_int(r3.x)*KR]);
    float f4 = bf2f(hb[(size_t)__float_as_int(r4.x)*KR]);
    a0 += r1.y*f1 + r2.y*f2 + r3.y*f3 + r4.y*f4;
    a1 += r1.z*f1 + r2.z*f2 + r3.z*f3 + r4.z*f4;
    a2 += r1.w*f1 + r2.w*f2 + r3.w*f3 + r4.w*f4;
    sw0 += r1.y + r2.y + r3.y + r4.y;
    sw1 += r1.z + r2.z + r3.z + r4.z;
    sw2 += r1.w + r2.w + r3.w + r4.w;
  }
  for (; p < end; ++p) {
    float4 r1 = rp[p];
    float f1 = bf2f(hb[(size_t)__float_as_int(r1.x)*KR]);
    a0 += r1.y*f1; a1 += r1.z*f1; a2 += r1.w*f1;
    sw0 += r1.y; sw1 += r1.z; sw2 += r1.w;
  }
  float fs = bf2f(hb[(size_t)n*KR]);
  a0 -= sw0*fs; a1 -= sw1*fs; a2 -= sw2*fs;
  unsigned short* gp = d_stackT + ((size_t)(b*NP + n))*KR + 384;
  gp[c]        = f2bf(a0/(1.f + fabsf(a0)));
  gp[CC + c]   = f2bf(a1/(1.f + fabsf(a1)));
  gp[2*CC + c] = f2bf(a2/(1.f + fabsf(a2)));
}

// ---- fused: reduce split-k partials -> xc/xs  |  x0 partials from hTwT ----
__global__ __launch_bounds__(256) void k_red_x0() {
  int blk = blockIdx.x;
  if (blk < 256) {
    int tid = blk*256 + threadIdx.x;
    int k = tid & 127;
    int c = (tid >> 7) & 127;
    int arr = (tid >> 14) & 1;
    int b = tid >> 15;
    int ch = c >> 6, cl = c & 63;
    int kh = k >> 6, kl = k & 63;
    int quad = ch*2 + kh;
    const float* p = d_part + ((size_t)(b*4 + quad)*G1CH)*2*4096 + arr*4096 + cl*64 + kl;
    float acc = 0.f;
    for (int t = 0; t < G1CH; t++) acc += p[(size_t)t*2*4096];
    if (arr == 0) d_xc[(b*CC + c)*KK + k] = acc;
    else          d_xs[(b*CC + c)*KK + k] = acc;
  } else {
    int bc = blk - 256;        // 0..313
    int chunk = bc % NCHK, b = bc / NCHK;
    int tid = threadIdx.x;
    int c = tid >> 1, half = tid & 1;
    const unsigned short* p = d_hTwT + ((size_t)(b*CC + c))*NP + chunk*128 + half*64;
    float acc = 0.f;
    #pragma unroll
    for (int i = 0; i < 8; i++) {
      ushort4 v0 = *(const ushort4*)&p[i*8];
      ushort4 v1 = *(const ushort4*)&p[i*8 + 4];
      acc += bf2f(v0.x) + bf2f(v0.y) + bf2f(v0.z) + bf2f(v0.w)
           + bf2f(v1.x) + bf2f(v1.y) + bf2f(v1.z) + bf2f(v1.w);
    }
    __shared__ float red[128][2];
    red[c][half] = acc;
    __syncthreads();
    if (half == 0) d_x0p[(b*NCHK + chunk)*CC + c] = red[c][0] + red[c][1];
  }
}

// ---- spectral mix, i-chunked (8 chunks of 16) -> partials ----
__global__ __launch_bounds__(128) void k_spec(const float* __restrict__ Wc,
                                              const float* __restrict__ Ws, int l) {
  int bo = blockIdx.x;          // b*CC + o
  int ch = blockIdx.y;          // 0..7
  int b = bo >> 7;
  int o = bo & 127;
  int k = threadIdx.x;
  int i0 = ch*16;
  const float* wcp = Wc + ((size_t)(l*CC + i0)*CC + o)*KK + k;
  const float* wsp = Ws + ((size_t)(l*CC + i0)*CC + o)*KK + k;
  float fc = 0.f, fs = 0.f;
  #pragma unroll 4
  for (int j = 0; j < 16; j++) {
    int i = i0 + j;
    float xcv = d_xc[(b*CC + i)*KK + k];
    float xsv = d_xs[(b*CC + i)*KK + k];
    float wcv = wcp[(size_t)j*CC*KK];
    float wsv = wsp[(size_t)j*CC*KK];
    fc += xcv*wcv - xsv*wsv;
    fs += xsv*wcv + xcv*wsv;
  }
  d_fcp[((size_t)bo*8 + ch)*KK + k] = fc;
  d_fsp[((size_t)bo*8 + ch)*KK + k] = fs;
}

// ---- fused: build A matrix [b][o][r] bf16  |  f0 + full bias ----
__global__ __launch_bounds__(128) void k_bA_f0(const float* __restrict__ wsw,
                                               const float* __restrict__ gwsw,
                                               const float* __restrict__ W0,
                                               const float* __restrict__ wsb,
                                               const float* __restrict__ gwsb, int l) {
  int blk = blockIdx.x;
  int t = threadIdx.x;
  if (blk < 256) {
    int bo = blk;
    int b = bo >> 7, o = bo & 127;
    float fc = 0.f, fs = 0.f;
    #pragma unroll
    for (int ch = 0; ch < 8; ch++) {
      fc += d_fcp[((size_t)bo*8 + ch)*KK + t];
      fs += d_fsp[((size_t)bo*8 + ch)*KK + t];
    }
    unsigned short* dst = d_Amatb + (size_t)bo*KR;
    dst[t]       = f2bf( 2.f*fc);
    dst[128 + t] = f2bf(-2.f*fs);
    dst[256 + t] = f2bf(wsw[(l*CC + o)*CC + t]);
    #pragma unroll
    for (int j = 0; j < 3; j++)
      dst[384 + j*128 + t] = f2bf(gwsw[(size_t)(l*CC + o)*GJ + j*128 + t]);
  } else {
    int b = blk - 256;
    int o = t;
    __shared__ float sx[CC];
    float xv = 0.f;
    for (int p = 0; p < NCHK; p++) xv += d_x0p[(b*NCHK + p)*CC + o];
    sx[o] = xv;
    __syncthreads();
    float acc = 0.f;
    for (int i = 0; i < CC; i++) acc += sx[i]*W0[(l*CC + i)*CC + o];
    d_bias[b*CC + o] = acc + wsb[l*CC + o] + gwsb[l*CC + o];
  }
}

// ---- fc1w transpose to [o2][c] bf16 ----
__global__ __launch_bounds__(128) void k_fc1w(const float* __restrict__ fc1w) {
  int c = blockIdx.x;
  int o2 = threadIdx.x;
  d_fc1wb[o2*CC + c] = f2bf(fc1w[c*FCC + o2]);
}

// ---- MFMA GEMM v8: 64n x 128o, 512 threads (8 waves = 4n x 2o), K-chunk 64.
// aux=1: h-slab + hTwT epilogue. aux=0: fused fc2 + residual -> out. ----
__global__ __launch_bounds__(512) void k_mfma(int koff, int K,
                                              const unsigned short* __restrict__ W, size_t wstride,
                                              const float* __restrict__ bias, int bias_stride,
                                              int gelu, int aux,
                                              const float* __restrict__ xvec,
                                              const float* __restrict__ tvec,
                                              const float* __restrict__ fc2w,
                                              const float* __restrict__ fc2b,
                                              float* __restrict__ outp) {
  __shared__ unsigned short As[2][64*72];    // 18.4 KB (reused as epilogue buffer)
  __shared__ unsigned short Bs[2][128*72];   // 36.9 KB
  __shared__ float sh_nw[64];
  int b = blockIdx.z;
  int n_base = blockIdx.x*64;
  int tid = threadIdx.x;
  int lane = tid & 63, wid = tid >> 6;       // 8 waves
  int wr = wid >> 1, wc = wid & 1;           // n-group (0..3), o-group (0..1)
  int q = lane >> 4, m = lane & 15;

  f32x4 acc[4];
  #pragma unroll
  for (int j = 0; j < 4; j++) acc[j] = (f32x4){0.f,0.f,0.f,0.f};

  const unsigned short* Wb = W + (size_t)b*wstride;
  const unsigned short* Ab = d_stackT + (size_t)b*NP*KR + koff;

#define STAGE(k0, d) { \
    { int rowA = tid >> 3; int e8A = (tid & 7)*8; \
      *(uint4*)&As[d][rowA*72 + e8A] = *(const uint4*)(Ab + (size_t)(n_base + rowA)*KR + (k0) + e8A); } \
    _Pragma("unroll") \
    for (int i_ = 0; i_ < 2; i_++) { \
      int idx_ = tid + i_*512; int rowB = idx_ >> 3; int e8B = (idx_ & 7)*8; \
      *(uint4*)&Bs[d][rowB*72 + e8B] = *(const uint4*)(Wb + (size_t)rowB*K + (k0) + e8B); } }

  STAGE(0, 0)
  int cur = 0;
  for (int k0 = 0; k0 < K; k0 += 64) {
    __syncthreads();
    if (k0 + 64 < K) STAGE(k0 + 64, cur ^ 1)
    bf16x8 a0 = *(const bf16x8*)&As[cur][(wr*16 + m)*72 + q*8];
    bf16x8 a1 = *(const bf16x8*)&As[cur][(wr*16 + m)*72 + 32 + q*8];
    #pragma unroll
    for (int ot = 0; ot < 4; ot++) {
      bf16x8 b0 = *(const bf16x8*)&Bs[cur][(wc*64 + ot*16 + m)*72 + q*8];
      acc[ot] = __builtin_amdgcn_mfma_f32_16x16x32_bf16(a0, b0, acc[ot], 0, 0, 0);
      bf16x8 b1 = *(const bf16x8*)&Bs[cur][(wc*64 + ot*16 + m)*72 + 32 + q*8];
      acc[ot] = __builtin_amdgcn_mfma_f32_16x16x32_bf16(a1, b1, acc[ot], 0, 0, 0);
    }
    cur ^= 1;
  }
#undef STAGE

  // ---- epilogue: bias+gelu -> bf16 into LDS (alias dead As) ----
  __syncthreads();
  unsigned short* Ep = &As[0][0];            // 64*132 = 8448 <= 9216 ushorts
  if (tid < 64) {
    int n = n_base + tid;
    sh_nw[tid] = (aux && n < NN) ? d_nw[b*NN + n] : 0.f;
  }
  const float* bp = bias + (size_t)b*bias_stride;
  int lrow = wr*16 + q*4;
  #pragma unroll
  for (int ot = 0; ot < 4; ot++) {
    int o = wc*64 + ot*16 + m;
    float bvv = bp[o];
    #pragma unroll
    for (int r = 0; r < 4; r++) {
      float v = acc[ot][r] + bvv;
      if (gelu) v = 0.5f*v*(1.f + erff(v*0.70710678118f));
      Ep[(lrow + r)*132 + o] = f2bf(v);
    }
  }
  __syncthreads();
  if (aux) {
    // h-slab rows: 64 rows x 128 cols, 16 ushorts/thread
    {
      int row = tid >> 3;
      int c16 = (tid & 7)*16;
      int n = n_base + row;
      if (n < NN) {
        uint4 v0 = *(uint4*)&Ep[row*132 + c16];
        uint4 v1 = *(uint4*)&Ep[row*132 + c16 + 8];
        unsigned short* dst = d_stackT + ((size_t)(b*NP + n))*KR + 256;
        *(uint4*)&dst[c16]     = v0;
        *(uint4*)&dst[c16 + 8] = v1;
      }
    }
    // hTwT transpose: 128 o-rows x 64 n-cols, 16 ushorts/thread
    {
      int o = tid >> 2;
      int j0 = (tid & 3)*16;
      unsigned short tmp[16];
      #pragma unroll
      for (int j = 0; j < 16; j++) {
        float hv = bf2f(Ep[(j0 + j)*132 + o]);
        tmp[j] = f2bf(hv * sh_nw[j0 + j]);
      }
      unsigned short* dst = d_hTwT + ((size_t)(b*CC + o))*NP + n_base + j0;
      *(uint4*)&dst[0] = *(uint4*)&tmp[0];
      *(uint4*)&dst[8] = *(uint4*)&tmp[8];
    }
  } else {
    // fused fc2 + residual: 8 threads per row reduce 128 o2
    int row = tid >> 3, j = tid & 7;
    int n = n_base + row;
    float p0 = 0.f, p1 = 0.f, p2 = 0.f;
    int o0 = j*16;
    #pragma unroll
    for (int oo = 0; oo < 16; oo++) {
      float uv = bf2f(Ep[row*132 + o0 + oo]);
      p0 += uv*fc2w[(o0+oo)*3 + 0];
      p1 += uv*fc2w[(o0+oo)*3 + 1];
      p2 += uv*fc2w[(o0+oo)*3 + 2];
    }
    #pragma unroll
    for (int s2 = 1; s2 < 8; s2 <<= 1) {
      p0 += __shfl_xor(p0, s2);
      p1 += __shfl_xor(p1, s2);
      p2 += __shfl_xor(p2, s2);
    }
    if (j == 0 && n < NN) {
      int bn = b*NN + n;
      float tv = tvec[bn];
      outp[bn*3 + 0] = xvec[bn*3 + 0] + tv*(p0 + fc2b[0]);
      outp[bn*3 + 1] = xvec[bn*3 + 1] + tv*(p1 + fc2b[1]);
      outp[bn*3 + 2] = xvec[bn*3 + 2] + tv*(p2 + fc2b[2]);
    }
  }
}

extern "C" void kernel_launch(void* const* d_in, const int* in_sizes, int n_in,
                              void* d_out, int out_size, void* d_ws, size_t ws_size,
                              hipStream_t stream) {
  const float* x     = (const float*)d_in[0];
  const float* t     = (const float*)d_in[1];
  const float* nodes = (const float*)d_in[3];
  const float* nodew = (const float*)d_in[4];
  const int*   edges = (const int*)d_in[5];
  const float* egw   = (const float*)d_in[6];
  const float* modes = (const float*)d_in[7];
  const float* spL   = (const float*)d_in[8];
  const float* fc0w  = (const float*)d_in[9];
  const float* fc0b  = (const float*)d_in[10];
  const float* Wc    = (const float*)d_in[11];
  const float* Ws    = (const float*)d_in[12];
  const float* W0    = (const float*)d_in[13];
  const float* wsw   = (const float*)d_in[14];
  const float* wsb   = (const float*)d_in[15];
  const float* gwsw  = (const float*)d_in[16];
  const float* gwsb  = (const float*)d_in[17];
  const float* fc1w  = (const float*)d_in[18];
  const float* fc1b  = (const float*)d_in[19];
  const float* fc2w  = (const float*)d_in[20];
  const float* fc2b  = (const float*)d_in[21];
  float* out = (float*)d_out;

  unsigned short* d_Amatb_p; (void)hipGetSymbolAddress((void**)&d_Amatb_p, HIP_SYMBOL(d_Amatb));
  unsigned short* d_fc1wb_p; (void)hipGetSymbolAddress((void**)&d_fc1wb_p, HIP_SYMBOL(d_fc1wb));
  float* d_bias_p;  (void)hipGetSymbolAddress((void**)&d_bias_p,  HIP_SYMBOL(d_bias));

  hipLaunchKernelGGL(k_basis, dim3(BB*NN), dim3(128), 0, stream, nodes, nodew, modes, spL);
  hipLaunchKernelGGL(k_basisT, dim3(628*BB), dim3(256), 0, stream);
  hipLaunchKernelGGL(k_h0, dim3(BB*NN*CC/256), dim3(256), 0, stream, x, t, fc0w, fc0b);
  hipLaunchKernelGGL(k_hT0, dim3(NCHK, BB), dim3(256), 0, stream);
  hipLaunchKernelGGL(k_fc1w, dim3(CC), dim3(FCC), 0, stream, fc1w);
  // CSR build (once; edges constant across layers)
  hipLaunchKernelGGL(k_csr_zero, dim3((BB*NN + 255)/256), dim3(256), 0, stream);
  hipLaunchKernelGGL(k_csr_count, dim3((BB*EE + 255)/256), dim3(256), 0, stream, edges);
  hipLaunchKernelGGL(k_csr_scan, dim3(BB), dim3(1024), 0, stream);
  hipLaunchKernelGGL(k_csr_scatter, dim3((BB*EE + 255)/256), dim3(256), 0, stream, edges, egw);

  for (int l = 0; l < LL; l++) {
    hipLaunchKernelGGL(k_gemm1m, dim3(G1CH, 4, BB), dim3(256), 0, stream);
    hipLaunchKernelGGL(k_grad_csr, dim3(BB*NN/2), dim3(256), 0, stream);
    hipLaunchKernelGGL(k_red_x0, dim3(256 + NCHK*BB), dim3(256), 0, stream);
    hipLaunchKernelGGL(k_spec, dim3(BB*CC, 8), dim3(128), 0, stream, Wc, Ws, l);
    hipLaunchKernelGGL(k_bA_f0, dim3(BB*CC + BB), dim3(128), 0, stream,
                       wsw, gwsw, W0, wsb, gwsb, l);
    hipLaunchKernelGGL(k_mfma, dim3(NP/64, 1, BB), dim3(512), 0, stream,
                       0, KR, d_Amatb_p, (size_t)CC*KR, d_bias_p, CC,
                       (l != LL-1) ? 1 : 0, 1,
                       (const float*)nullptr, (const float*)nullptr,
                       (const float*)nullptr, (const float*)nullptr, (float*)nullptr);
  }

  // fc1 via MFMA on the h slab, fc2+residual fused in epilogue (gelu=1, aux=0)
  hipLaunchKernelGGL(k_mfma, dim3(NP/64, 1, BB), dim3(512), 0, stream,
                     256, CC, d_fc1wb_p, (size_t)0, fc1b, 0, 1, 0,
                     x, t, fc2w, fc2b, out);
}